// Round 29
// baseline (56.365 us; speedup 1.0000x reference)
//
#include <hip/hip_runtime.h>
#include <hip/hip_bf16.h>

#define B 2
#define S 2048
#define E 128
#define H 8
#define HD 16
#define BH (B*H)

#define RPB 8    // rows per block (qkv_proj)
#define KT 128   // key tile (attn)

typedef __attribute__((ext_vector_type(8))) short bf16x8;
typedef __attribute__((ext_vector_type(4))) float f32x4;

__device__ __forceinline__ unsigned short f2b(float f) {   // f32->bf16 RNE
    const unsigned u = __float_as_uint(f);
    return (unsigned short)((u + 0x7FFFu + ((u >> 16) & 1u)) >> 16);
}
__device__ __forceinline__ float b2f(unsigned short u) {
    return __uint_as_float((unsigned)u << 16);
}

// ---- Pass A: compaction + tail-zero fused. Grid BH x 64 threads. ----
__global__ __launch_bounds__(64) void prep(
    const int* __restrict__ mask, const int* __restrict__ masked_p,
    int* __restrict__ pos, int* __restrict__ cnt,
    unsigned short* __restrict__ Kxg, unsigned short* __restrict__ Btg)
{
    const int bh = blockIdx.x;
    const int b = bh >> 3, h = bh & 7;
    const int lane = threadIdx.x;
    const int masked = *masked_p;

    int v[32];
    #pragma unroll
    for (int c = 0; c < 32; ++c)
        v[c] = mask[b * S + c * 64 + lane];

    int base = 0;
    #pragma unroll
    for (int c = 0; c < 32; ++c) {
        const bool keep = (masked != 0) || (v[c] != 0);
        const unsigned long long bal = __ballot(keep);
        if (h == 0) {
            const int my = base + (int)__popcll(bal & ((1ULL << lane) - 1ULL));
            pos[b * S + c * 64 + lane] = keep ? my : -1;
        }
        base += (int)__popcll(bal);
    }
    int cn = base;
    if (cn == 0) {                         // all masked: -1000 shift cancels
        if (h == 0) {
            #pragma unroll
            for (int c = 0; c < 32; ++c)
                pos[b * S + c * 64 + lane] = c * 64 + lane;
        }
        cn = S;
    }
    if (h == 0 && lane == 0) cnt[b] = cn;

    const int pad = ((cn + KT - 1) / KT) * KT;
    const int nrows = pad - cn;
    unsigned short* KxB = Kxg + (size_t)bh * S * 32;
    unsigned short* BtB = Btg + (size_t)bh * S * 32;
    for (int idx = lane; idx < nrows * 16; idx += 64) {
        const int row = cn + (idx >> 4), d = idx & 15;
        KxB[row * 32 + d]      = 0;
        KxB[row * 32 + 16 + d] = 0;
        BtB[((row >> 4) * 16 + d) * 32 + (row & 15)]      = 0;
        BtB[((row >> 4) * 16 + d) * 32 + (row & 15) + 16] = 0;
    }
}

// ---- Pass 0: QKV projection, weight-stream software prefetch. ----
__global__ __launch_bounds__(128) void qkv_proj(
    const float* __restrict__ x,
    const float* __restrict__ wq,
    const float* __restrict__ wk,
    const float* __restrict__ wv,
    const int* __restrict__ pos,
    float* __restrict__ Q,
    unsigned short* __restrict__ Kxg, unsigned short* __restrict__ Btg)
{
    __shared__ float xs[RPB][E];
    const int row0 = blockIdx.x * RPB;
    const int c    = threadIdx.x;
    #pragma unroll
    for (int rr = 0; rr < RPB; ++rr)
        xs[rr][c] = x[(size_t)(row0 + rr) * E + c];
    __syncthreads();

    float aq[RPB], ak[RPB], av[RPB];
    #pragma unroll
    for (int rr = 0; rr < RPB; ++rr) { aq[rr] = 0.f; ak[rr] = 0.f; av[rr] = 0.f; }

    // 4-wide i-groups, 1-group-deep prefetch: 12 loads in flight over 96 FMAs
    float nq[4], nk[4], nv[4];
    #pragma unroll
    for (int j = 0; j < 4; ++j) {
        nq[j] = wq[j * E + c];
        nk[j] = wk[j * E + c];
        nv[j] = wv[j * E + c];
    }
    for (int i = 0; i < E; i += 4) {
        float cq[4], ck[4], cv[4];
        #pragma unroll
        for (int j = 0; j < 4; ++j) { cq[j] = nq[j]; ck[j] = nk[j]; cv[j] = nv[j]; }
        if (i + 4 < E) {
            #pragma unroll
            for (int j = 0; j < 4; ++j) {
                nq[j] = wq[(i + 4 + j) * E + c];
                nk[j] = wk[(i + 4 + j) * E + c];
                nv[j] = wv[(i + 4 + j) * E + c];
            }
        }
        #pragma unroll
        for (int j = 0; j < 4; ++j) {
            #pragma unroll
            for (int rr = 0; rr < RPB; ++rr) {
                const float xv = xs[rr][i + j];
                aq[rr] = fmaf(xv, cq[j], aq[rr]);
                ak[rr] = fmaf(xv, ck[j], ak[rr]);
                av[rr] = fmaf(xv, cv[j], av[rr]);
            }
        }
    }

    const int h = c & 7, d = c >> 3;       // faithful split: col = d*8+h
    #pragma unroll
    for (int rr = 0; rr < RPB; ++rr) {
        const int row = row0 + rr;
        const int b = row >> 11, s = row & 2047;
        const int bh = b * H + h;
        Q[(((size_t)bh) * S + s) * HD + d] = aq[rr] * 0.25f;
        const int p_ = pos[row];
        if (p_ >= 0) {
            const unsigned short kh = f2b(ak[rr]);
            const unsigned short kl = f2b(ak[rr] - b2f(kh));
            const unsigned short vh = f2b(av[rr]);
            const unsigned short vl = f2b(av[rr] - b2f(vh));
            unsigned short* kx = Kxg + (size_t)bh * S * 32 + (size_t)p_ * 32;
            kx[d]      = kh;
            kx[16 + d] = kl;
            unsigned short* bt = Btg + (size_t)bh * S * 32
                               + ((size_t)(p_ >> 4) * 16 + d) * 32 + (p_ & 15);
            bt[0]  = vh;
            bt[16] = vl;
        }
    }
}

// ---- Pass 1: MFMA flash attention, 2-deep software-pipelined loads. ----
__global__ __launch_bounds__(128) void attn(
    const float* __restrict__ Q,
    const unsigned short* __restrict__ Kxg,
    const unsigned short* __restrict__ Btg,
    const int* __restrict__ cnt,
    float* __restrict__ out)
{
    const int bh    = blockIdx.y;
    const int b     = bh >> 3;
    const int h     = bh & 7;
    const int qtile = blockIdx.x;        // 0..63
    const int tid   = threadIdx.x;       // 0..127
    const int wid   = tid >> 6;
    const int lane  = tid & 63;
    const int col   = lane & 15;
    const int g     = lane >> 4;         // 0..3
    const int qrow0 = qtile * 32 + wid * 16;
    const int cn    = cnt[b];
    const int nt    = (cn + KT - 1) >> 7;

    const unsigned short* KxB = Kxg + (size_t)bh * S * 32;
    const unsigned short* BtB = Btg + (size_t)bh * S * 32;

    bf16x8 qh, ql;
    {
        const float* qp = Q + ((size_t)bh * S + qrow0 + col) * HD + 8 * (g & 1);
        #pragma unroll
        for (int i = 0; i < 8; ++i) {
            const float f = qp[i];
            const unsigned short hi = f2b(f);
            qh[i] = (short)hi;
            ql[i] = (short)f2b(f - b2f(hi));
        }
    }

    float m = -1e30f, l = 0.f;
    f32x4 acc = {0.f, 0.f, 0.f, 0.f};

#define LOADT(KA, VB, TBASE)                                              \
    {                                                                     \
        const int base_ = (TBASE);                                        \
        _Pragma("unroll")                                                 \
        for (int kb = 0; kb < 8; ++kb) {                                  \
            KA[kb] = *(const bf16x8*)(                                    \
                KxB + (size_t)(base_ + kb * 16 + col) * 32 + 8 * g);      \
            VB[kb] = *(const bf16x8*)(                                    \
                BtB + (size_t)((base_ >> 4) + kb) * 512 + col * 32 + 8 * g); \
        }                                                                 \
    }

#define COMPUTE(KA, VB, TBASE)                                            \
    {                                                                     \
        const int base_ = (TBASE);                                        \
        f32x4 sc[8];                                                      \
        _Pragma("unroll")                                                 \
        for (int kb = 0; kb < 8; ++kb) {                                  \
            f32x4 c_ = {0.f, 0.f, 0.f, 0.f};                              \
            c_ = __builtin_amdgcn_mfma_f32_16x16x32_bf16(KA[kb], qh, c_, 0, 0, 0); \
            c_ = __builtin_amdgcn_mfma_f32_16x16x32_bf16(KA[kb], ql, c_, 0, 0, 0); \
            sc[kb] = c_;                                                  \
        }                                                                 \
        if (base_ + KT > cn) {                                            \
            _Pragma("unroll")                                             \
            for (int kb = 0; kb < 8; ++kb)                                \
                _Pragma("unroll")                                         \
                for (int r = 0; r < 4; ++r)                               \
                    if (base_ + kb * 16 + 4 * g + r >= cn) sc[kb][r] = -1e30f; \
        }                                                                 \
        float tm = sc[0][0];                                              \
        _Pragma("unroll")                                                 \
        for (int kb = 0; kb < 8; ++kb)                                    \
            _Pragma("unroll")                                             \
            for (int r = 0; r < 4; ++r) tm = fmaxf(tm, sc[kb][r]);        \
        tm = fmaxf(tm, __shfl_xor(tm, 16));                               \
        tm = fmaxf(tm, __shfl_xor(tm, 32));                               \
        if (__any(tm > m)) {                                              \
            const float mn = fmaxf(m, tm);                                \
            const float alpha = __expf(m - mn);                           \
            m = mn;                                                       \
            l *= alpha;                                                   \
            _Pragma("unroll")                                             \
            for (int r = 0; r < 4; ++r)                                   \
                acc[r] *= __shfl(alpha, 4 * g + r);                       \
        }                                                                 \
        _Pragma("unroll")                                                 \
        for (int kb = 0; kb < 8; ++kb) {                                  \
            const float p0 = __expf(sc[kb][0] - m);                       \
            const float p1 = __expf(sc[kb][1] - m);                       \
            const float p2 = __expf(sc[kb][2] - m);                       \
            const float p3 = __expf(sc[kb][3] - m);                       \
            l += (p0 + p1) + (p2 + p3);                                   \
            const unsigned u01 = (unsigned)f2b(p0) | ((unsigned)f2b(p1) << 16); \
            const unsigned u23 = (unsigned)f2b(p2) | ((unsigned)f2b(p3) << 16); \
            const int s0 = col + 16 * (2 * (g & 1));                      \
            const int s1 = s0 + 16;                                       \
            union { unsigned u[4]; bf16x8 v; } pa;                        \
            pa.u[0] = (unsigned)__shfl((int)u01, s0);                     \
            pa.u[1] = (unsigned)__shfl((int)u23, s0);                     \
            pa.u[2] = (unsigned)__shfl((int)u01, s1);                     \
            pa.u[3] = (unsigned)__shfl((int)u23, s1);                     \
            acc = __builtin_amdgcn_mfma_f32_16x16x32_bf16(pa.v, VB[kb], acc, 0, 0, 0); \
        }                                                                 \
    }

    bf16x8 kaA[8], vbA[8], kaB[8], vbB[8];
    LOADT(kaA, vbA, 0);
    for (int kt = 0; kt < nt; kt += 2) {
        if (kt + 1 < nt) LOADT(kaB, vbB, (kt + 1) * KT);
        COMPUTE(kaA, vbA, kt * KT);
        if (kt + 1 < nt) {
            if (kt + 2 < nt) LOADT(kaA, vbA, (kt + 2) * KT);
            COMPUTE(kaB, vbB, (kt + 1) * KT);
        }
    }
#undef LOADT
#undef COMPUTE

    l += __shfl_xor(l, 16);
    l += __shfl_xor(l, 32);

    const float inv = 1.f / l;
    #pragma unroll
    for (int r = 0; r < 4; ++r) {
        const float ir = __shfl(inv, 4 * g + r);
        out[((size_t)(b * S + qrow0 + 4 * g + r)) * E + col * 8 + h] = acc[r] * ir;
    }
}

extern "C" void kernel_launch(void* const* d_in, const int* in_sizes, int n_in,
                              void* d_out, int out_size, void* d_ws, size_t ws_size,
                              hipStream_t stream) {
    int ix = 0, im0 = -1, isc = -1, iw[3] = {-1, -1, -1}, nw = 0;
    for (int i = 0; i < n_in; ++i) {
        const int sz = in_sizes[i];
        if (sz == B * S * E) ix = i;
        else if (sz == B * S) { if (im0 < 0) im0 = i; }
        else if (sz == E * E) { if (nw < 3) iw[nw++] = i; }
        else if (sz == 1 && isc < 0) isc = i;
    }
    if (im0 < 0) im0 = 1;
    if (isc < 0) isc = 3;
    if (nw < 3) { iw[0] = n_in - 3; iw[1] = n_in - 2; iw[2] = n_in - 1; }

    const float* x        = (const float*)d_in[ix];
    const int*   src_mask = (const int*)d_in[im0];
    const int*   masked_p = (const int*)d_in[isc];
    const float* wq       = (const float*)d_in[iw[0]];
    const float* wk       = (const float*)d_in[iw[1]];
    const float* wv       = (const float*)d_in[iw[2]];
    float*       out      = (float*)d_out;

    float*          Qw  = (float*)d_ws;
    unsigned short* Kxg = (unsigned short*)(Qw + (size_t)BH * S * HD);
    unsigned short* Btg = Kxg + (size_t)BH * S * 32;
    int*            pos = (int*)(Btg + (size_t)BH * S * 32);
    int*            cnt = pos + B * S;

    prep<<<BH, 64, 0, stream>>>(src_mask, masked_p, pos, cnt, Kxg, Btg);
    qkv_proj<<<B * S / RPB, 128, 0, stream>>>(x, wq, wk, wv, pos, Qw, Kxg, Btg);
    attn<<<dim3(S / 32, BH), 128, 0, stream>>>(Qw, Kxg, Btg, cnt, out);
}

// Round 30
// 51.234 us; speedup vs baseline: 1.1001x; 1.1001x over previous
//
#include <hip/hip_runtime.h>
#include <hip/hip_bf16.h>

#define B 2
#define S 2048
#define E 128
#define H 8
#define HD 16
#define BH (B*H)

#define RPB 8    // rows per block (qkv_proj)
#define KT 128   // key tile (attn)

typedef __attribute__((ext_vector_type(8))) short bf16x8;
typedef __attribute__((ext_vector_type(4))) float f32x4;

__device__ __forceinline__ unsigned short f2b(float f) {   // f32->bf16 RNE
    const unsigned u = __float_as_uint(f);
    return (unsigned short)((u + 0x7FFFu + ((u >> 16) & 1u)) >> 16);
}
__device__ __forceinline__ float b2f(unsigned short u) {
    return __uint_as_float((unsigned)u << 16);
}

// ---- Pass A: compaction + tail-zero fused. Grid BH x 64 threads. ----
// Bt layout (INTERLEAVED): Bt[bh][key>>4][dim][32] with slot = 2*(key&15)+part
// (part 0 = Vhi, part 1 = Vlo).
__global__ __launch_bounds__(64) void prep(
    const int* __restrict__ mask, const int* __restrict__ masked_p,
    int* __restrict__ pos, int* __restrict__ cnt,
    unsigned short* __restrict__ Kxg, unsigned short* __restrict__ Btg)
{
    const int bh = blockIdx.x;
    const int b = bh >> 3, h = bh & 7;
    const int lane = threadIdx.x;
    const int masked = *masked_p;

    int v[32];
    #pragma unroll
    for (int c = 0; c < 32; ++c)
        v[c] = mask[b * S + c * 64 + lane];

    int base = 0;
    #pragma unroll
    for (int c = 0; c < 32; ++c) {
        const bool keep = (masked != 0) || (v[c] != 0);
        const unsigned long long bal = __ballot(keep);
        if (h == 0) {
            const int my = base + (int)__popcll(bal & ((1ULL << lane) - 1ULL));
            pos[b * S + c * 64 + lane] = keep ? my : -1;
        }
        base += (int)__popcll(bal);
    }
    int cn = base;
    if (cn == 0) {                         // all masked: -1000 shift cancels
        if (h == 0) {
            #pragma unroll
            for (int c = 0; c < 32; ++c)
                pos[b * S + c * 64 + lane] = c * 64 + lane;
        }
        cn = S;
    }
    if (h == 0 && lane == 0) cnt[b] = cn;

    const int pad = ((cn + KT - 1) / KT) * KT;
    const int nrows = pad - cn;
    unsigned short* KxB = Kxg + (size_t)bh * S * 32;
    unsigned short* BtB = Btg + (size_t)bh * S * 32;
    for (int idx = lane; idx < nrows * 16; idx += 64) {
        const int row = cn + (idx >> 4), d = idx & 15;
        KxB[row * 32 + d]      = 0;
        KxB[row * 32 + 16 + d] = 0;
        // interleaved: slots 2*(row&15), 2*(row&15)+1
        BtB[((row >> 4) * 16 + d) * 32 + (row & 15) * 2]     = 0;
        BtB[((row >> 4) * 16 + d) * 32 + (row & 15) * 2 + 1] = 0;
    }
}

// ---- Pass 0: QKV projection; K/V written compacted, MFMA-ready bf16. ----
__global__ __launch_bounds__(128) void qkv_proj(
    const float* __restrict__ x,
    const float* __restrict__ wq,
    const float* __restrict__ wk,
    const float* __restrict__ wv,
    const int* __restrict__ pos,
    float* __restrict__ Q,
    unsigned short* __restrict__ Kxg, unsigned short* __restrict__ Btg)
{
    __shared__ float xs[RPB][E];
    const int row0 = blockIdx.x * RPB;
    const int c    = threadIdx.x;
    #pragma unroll
    for (int rr = 0; rr < RPB; ++rr)
        xs[rr][c] = x[(size_t)(row0 + rr) * E + c];
    __syncthreads();

    float aq[RPB], ak[RPB], av[RPB];
    #pragma unroll
    for (int rr = 0; rr < RPB; ++rr) { aq[rr] = 0.f; ak[rr] = 0.f; av[rr] = 0.f; }

    for (int i = 0; i < E; ++i) {
        const float wqv = wq[i * E + c];
        const float wkv = wk[i * E + c];
        const float wvv = wv[i * E + c];
        #pragma unroll
        for (int rr = 0; rr < RPB; ++rr) {
            const float xv = xs[rr][i];
            aq[rr] = fmaf(xv, wqv, aq[rr]);
            ak[rr] = fmaf(xv, wkv, ak[rr]);
            av[rr] = fmaf(xv, wvv, av[rr]);
        }
    }

    const int h = c & 7, d = c >> 3;       // faithful split: col = d*8+h
    #pragma unroll
    for (int rr = 0; rr < RPB; ++rr) {
        const int row = row0 + rr;
        const int b = row >> 11, s = row & 2047;
        const int bh = b * H + h;
        Q[(((size_t)bh) * S + s) * HD + d] = aq[rr] * 0.25f;
        const int p_ = pos[row];
        if (p_ >= 0) {
            const unsigned short kh = f2b(ak[rr]);
            const unsigned short kl = f2b(ak[rr] - b2f(kh));
            const unsigned short vh = f2b(av[rr]);
            const unsigned short vl = f2b(av[rr] - b2f(vh));
            unsigned short* kx = Kxg + (size_t)bh * S * 32 + (size_t)p_ * 32;
            kx[d]      = kh;
            kx[16 + d] = kl;
            // interleaved V: hi,lo adjacent -> one aligned u32 store
            unsigned short* bt = Btg + (size_t)bh * S * 32
                               + ((size_t)(p_ >> 4) * 16 + d) * 32 + (p_ & 15) * 2;
            *(unsigned*)bt = (unsigned)vh | ((unsigned)vl << 16);
        }
    }
}

// ---- Pass 1: MFMA flash attention, zero-shuffle PV. ----
// Block 128 = 2 independent waves; wave handles 16 queries, all keys.
// Interleaved V slot layout makes the PV A-frag lane-local: pa.u[r] =
// dup(f2b(p_r)) of THIS lane's own scores. 2-deep pipelined global loads.
__global__ __launch_bounds__(128) void attn(
    const float* __restrict__ Q,
    const unsigned short* __restrict__ Kxg,
    const unsigned short* __restrict__ Btg,
    const int* __restrict__ cnt,
    float* __restrict__ out)
{
    const int bh    = blockIdx.y;
    const int b     = bh >> 3;
    const int h     = bh & 7;
    const int qtile = blockIdx.x;        // 0..63
    const int tid   = threadIdx.x;       // 0..127
    const int wid   = tid >> 6;
    const int lane  = tid & 63;
    const int col   = lane & 15;
    const int g     = lane >> 4;         // 0..3
    const int qrow0 = qtile * 32 + wid * 16;
    const int cn    = cnt[b];
    const int nt    = (cn + KT - 1) >> 7;

    const unsigned short* KxB = Kxg + (size_t)bh * S * 32;
    const unsigned short* BtB = Btg + (size_t)bh * S * 32;

    bf16x8 qh, ql;
    {
        const float* qp = Q + ((size_t)bh * S + qrow0 + col) * HD + 8 * (g & 1);
        #pragma unroll
        for (int i = 0; i < 8; ++i) {
            const float f = qp[i];
            const unsigned short hi = f2b(f);
            qh[i] = (short)hi;
            ql[i] = (short)f2b(f - b2f(hi));
        }
    }

    float m = -1e30f, l = 0.f;
    f32x4 acc = {0.f, 0.f, 0.f, 0.f};

#define LOADT(KA, VB, TBASE)                                              \
    {                                                                     \
        const int base_ = (TBASE);                                        \
        _Pragma("unroll")                                                 \
        for (int kb = 0; kb < 8; ++kb) {                                  \
            KA[kb] = *(const bf16x8*)(                                    \
                KxB + (size_t)(base_ + kb * 16 + col) * 32 + 8 * g);      \
            VB[kb] = *(const bf16x8*)(                                    \
                BtB + (size_t)((base_ >> 4) + kb) * 512 + col * 32 + 8 * g); \
        }                                                                 \
    }

#define COMPUTE(KA, VB, TBASE)                                            \
    {                                                                     \
        const int base_ = (TBASE);                                        \
        f32x4 sc[8];                                                      \
        _Pragma("unroll")                                                 \
        for (int kb = 0; kb < 8; ++kb) {                                  \
            f32x4 c_ = {0.f, 0.f, 0.f, 0.f};                              \
            c_ = __builtin_amdgcn_mfma_f32_16x16x32_bf16(KA[kb], qh, c_, 0, 0, 0); \
            c_ = __builtin_amdgcn_mfma_f32_16x16x32_bf16(KA[kb], ql, c_, 0, 0, 0); \
            sc[kb] = c_;                                                  \
        }                                                                 \
        if (base_ + KT > cn) {                                            \
            _Pragma("unroll")                                             \
            for (int kb = 0; kb < 8; ++kb)                                \
                _Pragma("unroll")                                         \
                for (int r = 0; r < 4; ++r)                               \
                    if (base_ + kb * 16 + 4 * g + r >= cn) sc[kb][r] = -1e30f; \
        }                                                                 \
        float tm = sc[0][0];                                              \
        _Pragma("unroll")                                                 \
        for (int kb = 0; kb < 8; ++kb)                                    \
            _Pragma("unroll")                                             \
            for (int r = 0; r < 4; ++r) tm = fmaxf(tm, sc[kb][r]);        \
        tm = fmaxf(tm, __shfl_xor(tm, 16));                               \
        tm = fmaxf(tm, __shfl_xor(tm, 32));                               \
        if (__any(tm > m)) {                                              \
            const float mn = fmaxf(m, tm);                                \
            const float alpha = __expf(m - mn);                           \
            m = mn;                                                       \
            l *= alpha;                                                   \
            _Pragma("unroll")                                             \
            for (int r = 0; r < 4; ++r)                                   \
                acc[r] *= __shfl(alpha, 4 * g + r);                       \
        }                                                                 \
        _Pragma("unroll")                                                 \
        for (int kb = 0; kb < 8; ++kb) {                                  \
            const float p0 = __expf(sc[kb][0] - m);                       \
            const float p1 = __expf(sc[kb][1] - m);                       \
            const float p2 = __expf(sc[kb][2] - m);                       \
            const float p3 = __expf(sc[kb][3] - m);                       \
            l += (p0 + p1) + (p2 + p3);                                   \
            union { unsigned u[4]; bf16x8 v; } pa;                       \
            const unsigned b0 = (unsigned)f2b(p0);                        \
            const unsigned b1 = (unsigned)f2b(p1);                        \
            const unsigned b2 = (unsigned)f2b(p2);                        \
            const unsigned b3 = (unsigned)f2b(p3);                        \
            pa.u[0] = b0 | (b0 << 16);                                    \
            pa.u[1] = b1 | (b1 << 16);                                    \
            pa.u[2] = b2 | (b2 << 16);                                    \
            pa.u[3] = b3 | (b3 << 16);                                    \
            acc = __builtin_amdgcn_mfma_f32_16x16x32_bf16(pa.v, VB[kb], acc, 0, 0, 0); \
        }                                                                 \
    }

    bf16x8 kaA[8], vbA[8], kaB[8], vbB[8];
    LOADT(kaA, vbA, 0);
    for (int kt = 0; kt < nt; kt += 2) {
        if (kt + 1 < nt) LOADT(kaB, vbB, (kt + 1) * KT);
        COMPUTE(kaA, vbA, kt * KT);
        if (kt + 1 < nt) {
            if (kt + 2 < nt) LOADT(kaA, vbA, (kt + 2) * KT);
            COMPUTE(kaB, vbB, (kt + 1) * KT);
        }
    }
#undef LOADT
#undef COMPUTE

    // l is per-lane partial: reduce across g-groups (per query col)
    l += __shfl_xor(l, 16);
    l += __shfl_xor(l, 32);

    const float inv = 1.f / l;
    #pragma unroll
    for (int r = 0; r < 4; ++r) {
        const float ir = __shfl(inv, 4 * g + r);
        out[((size_t)(b * S + qrow0 + 4 * g + r)) * E + col * 8 + h] = acc[r] * ir;
    }
}

extern "C" void kernel_launch(void* const* d_in, const int* in_sizes, int n_in,
                              void* d_out, int out_size, void* d_ws, size_t ws_size,
                              hipStream_t stream) {
    int ix = 0, im0 = -1, isc = -1, iw[3] = {-1, -1, -1}, nw = 0;
    for (int i = 0; i < n_in; ++i) {
        const int sz = in_sizes[i];
        if (sz == B * S * E) ix = i;
        else if (sz == B * S) { if (im0 < 0) im0 = i; }
        else if (sz == E * E) { if (nw < 3) iw[nw++] = i; }
        else if (sz == 1 && isc < 0) isc = i;
    }
    if (im0 < 0) im0 = 1;
    if (isc < 0) isc = 3;
    if (nw < 3) { iw[0] = n_in - 3; iw[1] = n_in - 2; iw[2] = n_in - 1; }

    const float* x        = (const float*)d_in[ix];
    const int*   src_mask = (const int*)d_in[im0];
    const int*   masked_p = (const int*)d_in[isc];
    const float* wq       = (const float*)d_in[iw[0]];
    const float* wk       = (const float*)d_in[iw[1]];
    const float* wv       = (const float*)d_in[iw[2]];
    float*       out      = (float*)d_out;

    float*          Qw  = (float*)d_ws;
    unsigned short* Kxg = (unsigned short*)(Qw + (size_t)BH * S * HD);
    unsigned short* Btg = Kxg + (size_t)BH * S * 32;
    int*            pos = (int*)(Btg + (size_t)BH * S * 32);
    int*            cnt = pos + B * S;

    prep<<<BH, 64, 0, stream>>>(src_mask, masked_p, pos, cnt, Kxg, Btg);
    qkv_proj<<<B * S / RPB, 128, 0, stream>>>(x, wq, wk, wv, pos, Qw, Kxg, Btg);
    attn<<<dim3(S / 32, BH), 128, 0, stream>>>(Qw, Kxg, Btg, cnt, out);
}

// Round 31
// 49.081 us; speedup vs baseline: 1.1484x; 1.0439x over previous
//
#include <hip/hip_runtime.h>
#include <hip/hip_bf16.h>

#define B 2
#define S 2048
#define E 128
#define H 8
#define HD 16
#define BH (B*H)

#define RPB 8    // rows per block (qkv_proj)
#define KT 128   // key tile (attn)

typedef __attribute__((ext_vector_type(8))) short bf16x8;
typedef __attribute__((ext_vector_type(4))) float f32x4;

__device__ __forceinline__ unsigned short f2b(float f) {   // f32->bf16 RNE
    const unsigned u = __float_as_uint(f);
    return (unsigned short)((u + 0x7FFFu + ((u >> 16) & 1u)) >> 16);
}
__device__ __forceinline__ float b2f(unsigned short u) {
    return __uint_as_float((unsigned)u << 16);
}

// ---- Pass A: compaction + tail-zero fused. Grid BH x 64 threads. ----
// Bt layout (INTERLEAVED): Bt[bh][key>>4][dim][32], slot = 2*(key&15)+part.
__global__ __launch_bounds__(64) void prep(
    const int* __restrict__ mask, const int* __restrict__ masked_p,
    int* __restrict__ pos, int* __restrict__ cnt,
    unsigned short* __restrict__ Kxg, unsigned short* __restrict__ Btg)
{
    const int bh = blockIdx.x;
    const int b = bh >> 3, h = bh & 7;
    const int lane = threadIdx.x;
    const int masked = *masked_p;

    int v[32];
    #pragma unroll
    for (int c = 0; c < 32; ++c)
        v[c] = mask[b * S + c * 64 + lane];

    int base = 0;
    #pragma unroll
    for (int c = 0; c < 32; ++c) {
        const bool keep = (masked != 0) || (v[c] != 0);
        const unsigned long long bal = __ballot(keep);
        if (h == 0) {
            const int my = base + (int)__popcll(bal & ((1ULL << lane) - 1ULL));
            pos[b * S + c * 64 + lane] = keep ? my : -1;
        }
        base += (int)__popcll(bal);
    }
    int cn = base;
    if (cn == 0) {                         // all masked: -1000 shift cancels
        if (h == 0) {
            #pragma unroll
            for (int c = 0; c < 32; ++c)
                pos[b * S + c * 64 + lane] = c * 64 + lane;
        }
        cn = S;
    }
    if (h == 0 && lane == 0) cnt[b] = cn;

    const int pad = ((cn + KT - 1) / KT) * KT;
    const int nrows = pad - cn;
    unsigned short* KxB = Kxg + (size_t)bh * S * 32;
    unsigned short* BtB = Btg + (size_t)bh * S * 32;
    for (int idx = lane; idx < nrows * 16; idx += 64) {
        const int row = cn + (idx >> 4), d = idx & 15;
        KxB[row * 32 + d]      = 0;
        KxB[row * 32 + 16 + d] = 0;
        BtB[((row >> 4) * 16 + d) * 32 + (row & 15) * 2]     = 0;
        BtB[((row >> 4) * 16 + d) * 32 + (row & 15) * 2 + 1] = 0;
    }
}

// ---- Pass 0: QKV projection, 3-way matrix split (384 thr = 6 waves). ----
// Thread group (tid>>7) owns one matrix; per-thread serial work 3x smaller,
// waves/SIMD 1 -> 3. Accumulation order per output identical to before.
__global__ __launch_bounds__(384) void qkv_proj(
    const float* __restrict__ x,
    const float* __restrict__ wq,
    const float* __restrict__ wk,
    const float* __restrict__ wv,
    const int* __restrict__ pos,
    float* __restrict__ Q,
    unsigned short* __restrict__ Kxg, unsigned short* __restrict__ Btg)
{
    __shared__ float xs[RPB][E];
    const int row0 = blockIdx.x * RPB;
    const int tid  = threadIdx.x;        // 0..383
    const int mat  = tid >> 7;           // 0=q, 1=k, 2=v (wave-uniform)
    const int c    = tid & 127;          // output column

    for (int idx = tid; idx < RPB * E; idx += 384)
        ((float*)xs)[idx] = x[(size_t)row0 * E + idx];
    __syncthreads();

    const float* w = (mat == 0) ? wq : (mat == 1) ? wk : wv;
    float a[RPB];
    #pragma unroll
    for (int rr = 0; rr < RPB; ++rr) a[rr] = 0.f;

    for (int i = 0; i < E; ++i) {
        const float wv_ = w[i * E + c];
        #pragma unroll
        for (int rr = 0; rr < RPB; ++rr)
            a[rr] = fmaf(xs[rr][i], wv_, a[rr]);
    }

    const int h = c & 7, d = c >> 3;     // faithful split: col = d*8+h
    if (mat == 0) {
        #pragma unroll
        for (int rr = 0; rr < RPB; ++rr) {
            const int row = row0 + rr;
            const int b = row >> 11, s = row & 2047;
            Q[(((size_t)(b * H + h)) * S + s) * HD + d] = a[rr] * 0.25f;
        }
    } else if (mat == 1) {
        #pragma unroll
        for (int rr = 0; rr < RPB; ++rr) {
            const int row = row0 + rr;
            const int p_ = pos[row];
            if (p_ >= 0) {
                const int b = row >> 11;
                const unsigned short kh = f2b(a[rr]);
                const unsigned short kl = f2b(a[rr] - b2f(kh));
                unsigned short* kx = Kxg + (size_t)(b * H + h) * S * 32
                                   + (size_t)p_ * 32;
                kx[d]      = kh;
                kx[16 + d] = kl;
            }
        }
    } else {
        #pragma unroll
        for (int rr = 0; rr < RPB; ++rr) {
            const int row = row0 + rr;
            const int p_ = pos[row];
            if (p_ >= 0) {
                const int b = row >> 11;
                const unsigned short vh = f2b(a[rr]);
                const unsigned short vl = f2b(a[rr] - b2f(vh));
                unsigned short* bt = Btg + (size_t)(b * H + h) * S * 32
                                   + ((size_t)(p_ >> 4) * 16 + d) * 32
                                   + (p_ & 15) * 2;
                *(unsigned*)bt = (unsigned)vh | ((unsigned)vl << 16);
            }
        }
    }
}

// ---- Pass 1: MFMA flash attention, zero-shuffle PV (round-30 best). ----
__global__ __launch_bounds__(128) void attn(
    const float* __restrict__ Q,
    const unsigned short* __restrict__ Kxg,
    const unsigned short* __restrict__ Btg,
    const int* __restrict__ cnt,
    float* __restrict__ out)
{
    const int bh    = blockIdx.y;
    const int b     = bh >> 3;
    const int h     = bh & 7;
    const int qtile = blockIdx.x;        // 0..63
    const int tid   = threadIdx.x;       // 0..127
    const int wid   = tid >> 6;
    const int lane  = tid & 63;
    const int col   = lane & 15;
    const int g     = lane >> 4;         // 0..3
    const int qrow0 = qtile * 32 + wid * 16;
    const int cn    = cnt[b];
    const int nt    = (cn + KT - 1) >> 7;

    const unsigned short* KxB = Kxg + (size_t)bh * S * 32;
    const unsigned short* BtB = Btg + (size_t)bh * S * 32;

    bf16x8 qh, ql;
    {
        const float* qp = Q + ((size_t)bh * S + qrow0 + col) * HD + 8 * (g & 1);
        #pragma unroll
        for (int i = 0; i < 8; ++i) {
            const float f = qp[i];
            const unsigned short hi = f2b(f);
            qh[i] = (short)hi;
            ql[i] = (short)f2b(f - b2f(hi));
        }
    }

    float m = -1e30f, l = 0.f;
    f32x4 acc = {0.f, 0.f, 0.f, 0.f};

#define LOADT(KA, VB, TBASE)                                              \
    {                                                                     \
        const int base_ = (TBASE);                                        \
        _Pragma("unroll")                                                 \
        for (int kb = 0; kb < 8; ++kb) {                                  \
            KA[kb] = *(const bf16x8*)(                                    \
                KxB + (size_t)(base_ + kb * 16 + col) * 32 + 8 * g);      \
            VB[kb] = *(const bf16x8*)(                                    \
                BtB + (size_t)((base_ >> 4) + kb) * 512 + col * 32 + 8 * g); \
        }                                                                 \
    }

#define COMPUTE(KA, VB, TBASE)                                            \
    {                                                                     \
        const int base_ = (TBASE);                                        \
        f32x4 sc[8];                                                      \
        _Pragma("unroll")                                                 \
        for (int kb = 0; kb < 8; ++kb) {                                  \
            f32x4 c_ = {0.f, 0.f, 0.f, 0.f};                              \
            c_ = __builtin_amdgcn_mfma_f32_16x16x32_bf16(KA[kb], qh, c_, 0, 0, 0); \
            c_ = __builtin_amdgcn_mfma_f32_16x16x32_bf16(KA[kb], ql, c_, 0, 0, 0); \
            sc[kb] = c_;                                                  \
        }                                                                 \
        if (base_ + KT > cn) {                                            \
            _Pragma("unroll")                                             \
            for (int kb = 0; kb < 8; ++kb)                                \
                _Pragma("unroll")                                         \
                for (int r = 0; r < 4; ++r)                               \
                    if (base_ + kb * 16 + 4 * g + r >= cn) sc[kb][r] = -1e30f; \
        }                                                                 \
        float tm = sc[0][0];                                              \
        _Pragma("unroll")                                                 \
        for (int kb = 0; kb < 8; ++kb)                                    \
            _Pragma("unroll")                                             \
            for (int r = 0; r < 4; ++r) tm = fmaxf(tm, sc[kb][r]);        \
        tm = fmaxf(tm, __shfl_xor(tm, 16));                               \
        tm = fmaxf(tm, __shfl_xor(tm, 32));                               \
        if (__any(tm > m)) {                                              \
            const float mn = fmaxf(m, tm);                                \
            const float alpha = __expf(m - mn);                           \
            m = mn;                                                       \
            l *= alpha;                                                   \
            _Pragma("unroll")                                             \
            for (int r = 0; r < 4; ++r)                                   \
                acc[r] *= __shfl(alpha, 4 * g + r);                       \
        }                                                                 \
        _Pragma("unroll")                                                 \
        for (int kb = 0; kb < 8; ++kb) {                                  \
            const float p0 = __expf(sc[kb][0] - m);                       \
            const float p1 = __expf(sc[kb][1] - m);                       \
            const float p2 = __expf(sc[kb][2] - m);                       \
            const float p3 = __expf(sc[kb][3] - m);                       \
            l += (p0 + p1) + (p2 + p3);                                   \
            union { unsigned u[4]; bf16x8 v; } pa;                       \
            const unsigned b0 = (unsigned)f2b(p0);                        \
            const unsigned b1 = (unsigned)f2b(p1);                        \
            const unsigned b2 = (unsigned)f2b(p2);                        \
            const unsigned b3 = (unsigned)f2b(p3);                        \
            pa.u[0] = b0 | (b0 << 16);                                    \
            pa.u[1] = b1 | (b1 << 16);                                    \
            pa.u[2] = b2 | (b2 << 16);                                    \
            pa.u[3] = b3 | (b3 << 16);                                    \
            acc = __builtin_amdgcn_mfma_f32_16x16x32_bf16(pa.v, VB[kb], acc, 0, 0, 0); \
        }                                                                 \
    }

    bf16x8 kaA[8], vbA[8], kaB[8], vbB[8];
    LOADT(kaA, vbA, 0);
    for (int kt = 0; kt < nt; kt += 2) {
        if (kt + 1 < nt) LOADT(kaB, vbB, (kt + 1) * KT);
        COMPUTE(kaA, vbA, kt * KT);
        if (kt + 1 < nt) {
            if (kt + 2 < nt) LOADT(kaA, vbA, (kt + 2) * KT);
            COMPUTE(kaB, vbB, (kt + 1) * KT);
        }
    }
#undef LOADT
#undef COMPUTE

    l += __shfl_xor(l, 16);
    l += __shfl_xor(l, 32);

    const float inv = 1.f / l;
    #pragma unroll
    for (int r = 0; r < 4; ++r) {
        const float ir = __shfl(inv, 4 * g + r);
        out[((size_t)(b * S + qrow0 + 4 * g + r)) * E + col * 8 + h] = acc[r] * ir;
    }
}

extern "C" void kernel_launch(void* const* d_in, const int* in_sizes, int n_in,
                              void* d_out, int out_size, void* d_ws, size_t ws_size,
                              hipStream_t stream) {
    int ix = 0, im0 = -1, isc = -1, iw[3] = {-1, -1, -1}, nw = 0;
    for (int i = 0; i < n_in; ++i) {
        const int sz = in_sizes[i];
        if (sz == B * S * E) ix = i;
        else if (sz == B * S) { if (im0 < 0) im0 = i; }
        else if (sz == E * E) { if (nw < 3) iw[nw++] = i; }
        else if (sz == 1 && isc < 0) isc = i;
    }
    if (im0 < 0) im0 = 1;
    if (isc < 0) isc = 3;
    if (nw < 3) { iw[0] = n_in - 3; iw[1] = n_in - 2; iw[2] = n_in - 1; }

    const float* x        = (const float*)d_in[ix];
    const int*   src_mask = (const int*)d_in[im0];
    const int*   masked_p = (const int*)d_in[isc];
    const float* wq       = (const float*)d_in[iw[0]];
    const float* wk       = (const float*)d_in[iw[1]];
    const float* wv       = (const float*)d_in[iw[2]];
    float*       out      = (float*)d_out;

    float*          Qw  = (float*)d_ws;
    unsigned short* Kxg = (unsigned short*)(Qw + (size_t)BH * S * HD);
    unsigned short* Btg = Kxg + (size_t)BH * S * 32;
    int*            pos = (int*)(Btg + (size_t)BH * S * 32);
    int*            cnt = pos + B * S;

    prep<<<BH, 64, 0, stream>>>(src_mask, masked_p, pos, cnt, Kxg, Btg);
    qkv_proj<<<B * S / RPB, 384, 0, stream>>>(x, wq, wk, wv, pos, Qw, Kxg, Btg);
    attn<<<dim3(S / 32, BH), 128, 0, stream>>>(Qw, Kxg, Btg, cnt, out);
}

// Round 33
// 48.555 us; speedup vs baseline: 1.1608x; 1.0108x over previous
//
#include <hip/hip_runtime.h>
#include <hip/hip_bf16.h>

#define B 2
#define S 2048
#define E 128
#define H 8
#define HD 16
#define BH (B*H)

#define RPB 8    // rows per block (qkv_proj)
#define KT 64    // key tile (attn)

typedef __attribute__((ext_vector_type(8))) short bf16x8;
typedef __attribute__((ext_vector_type(4))) float f32x4;

__device__ __forceinline__ unsigned short f2b(float f) {   // f32->bf16 RNE
    const unsigned u = __float_as_uint(f);
    return (unsigned short)((u + 0x7FFFu + ((u >> 16) & 1u)) >> 16);
}
__device__ __forceinline__ float b2f(unsigned short u) {
    return __uint_as_float((unsigned)u << 16);
}

// ---- Pass A: compaction + tail-zero fused. Grid BH x 64 threads. ----
// Bt layout (INTERLEAVED): Bt[bh][key>>4][dim][32], slot = 2*(key&15)+part.
__global__ __launch_bounds__(64) void prep(
    const int* __restrict__ mask, const int* __restrict__ masked_p,
    int* __restrict__ pos, int* __restrict__ cnt,
    unsigned short* __restrict__ Kxg, unsigned short* __restrict__ Btg)
{
    const int bh = blockIdx.x;
    const int b = bh >> 3, h = bh & 7;
    const int lane = threadIdx.x;
    const int masked = *masked_p;

    int v[32];
    #pragma unroll
    for (int c = 0; c < 32; ++c)
        v[c] = mask[b * S + c * 64 + lane];

    int base = 0;
    #pragma unroll
    for (int c = 0; c < 32; ++c) {
        const bool keep = (masked != 0) || (v[c] != 0);
        const unsigned long long bal = __ballot(keep);
        if (h == 0) {
            const int my = base + (int)__popcll(bal & ((1ULL << lane) - 1ULL));
            pos[b * S + c * 64 + lane] = keep ? my : -1;
        }
        base += (int)__popcll(bal);
    }
    int cn = base;
    if (cn == 0) {                         // all masked: -1000 shift cancels
        if (h == 0) {
            #pragma unroll
            for (int c = 0; c < 32; ++c)
                pos[b * S + c * 64 + lane] = c * 64 + lane;
        }
        cn = S;
    }
    if (h == 0 && lane == 0) cnt[b] = cn;

    const int pad = ((cn + KT - 1) / KT) * KT;   // 64-granule
    const int nrows = pad - cn;
    unsigned short* KxB = Kxg + (size_t)bh * S * 32;
    unsigned short* BtB = Btg + (size_t)bh * S * 32;
    for (int idx = lane; idx < nrows * 16; idx += 64) {
        const int row = cn + (idx >> 4), d = idx & 15;
        KxB[row * 32 + d]      = 0;
        KxB[row * 32 + 16 + d] = 0;
        BtB[((row >> 4) * 16 + d) * 32 + (row & 15) * 2]     = 0;
        BtB[((row >> 4) * 16 + d) * 32 + (row & 15) * 2 + 1] = 0;
    }
}

// ---- Pass 0: QKV projection, 3-way matrix split (384 thr = 6 waves). ----
__global__ __launch_bounds__(384) void qkv_proj(
    const float* __restrict__ x,
    const float* __restrict__ wq,
    const float* __restrict__ wk,
    const float* __restrict__ wv,
    const int* __restrict__ pos,
    float* __restrict__ Q,
    unsigned short* __restrict__ Kxg, unsigned short* __restrict__ Btg)
{
    __shared__ float xs[RPB][E];
    const int row0 = blockIdx.x * RPB;
    const int tid  = threadIdx.x;        // 0..383
    const int mat  = tid >> 7;           // 0=q, 1=k, 2=v (wave-uniform)
    const int c    = tid & 127;          // output column

    for (int idx = tid; idx < RPB * E; idx += 384)
        ((float*)xs)[idx] = x[(size_t)row0 * E + idx];
    __syncthreads();

    const float* w = (mat == 0) ? wq : (mat == 1) ? wk : wv;
    float a[RPB];
    #pragma unroll
    for (int rr = 0; rr < RPB; ++rr) a[rr] = 0.f;

    for (int i = 0; i < E; ++i) {
        const float wv_ = w[i * E + c];
        #pragma unroll
        for (int rr = 0; rr < RPB; ++rr)
            a[rr] = fmaf(xs[rr][i], wv_, a[rr]);
    }

    const int h = c & 7, d = c >> 3;     // faithful split: col = d*8+h
    if (mat == 0) {
        #pragma unroll
        for (int rr = 0; rr < RPB; ++rr) {
            const int row = row0 + rr;
            const int b = row >> 11, s = row & 2047;
            Q[(((size_t)(b * H + h)) * S + s) * HD + d] = a[rr] * 0.25f;
        }
    } else if (mat == 1) {
        #pragma unroll
        for (int rr = 0; rr < RPB; ++rr) {
            const int row = row0 + rr;
            const int p_ = pos[row];
            if (p_ >= 0) {
                const int b = row >> 11;
                const unsigned short kh = f2b(a[rr]);
                const unsigned short kl = f2b(a[rr] - b2f(kh));
                unsigned short* kx = Kxg + (size_t)(b * H + h) * S * 32
                                   + (size_t)p_ * 32;
                kx[d]      = kh;
                kx[16 + d] = kl;
            }
        }
    } else {
        #pragma unroll
        for (int rr = 0; rr < RPB; ++rr) {
            const int row = row0 + rr;
            const int p_ = pos[row];
            if (p_ >= 0) {
                const int b = row >> 11;
                const unsigned short vh = f2b(a[rr]);
                const unsigned short vl = f2b(a[rr] - b2f(vh));
                unsigned short* bt = Btg + (size_t)(b * H + h) * S * 32
                                   + ((size_t)(p_ >> 4) * 16 + d) * 32
                                   + (p_ & 15) * 2;
                *(unsigned*)bt = (unsigned)vh | ((unsigned)vl << 16);
            }
        }
    }
}

// ---- Pass 1: MFMA flash attention, KT=64, zero-shuffle PV (manual pack). --
__global__ __launch_bounds__(128) void attn(
    const float* __restrict__ Q,
    const unsigned short* __restrict__ Kxg,
    const unsigned short* __restrict__ Btg,
    const int* __restrict__ cnt,
    float* __restrict__ out)
{
    const int bh    = blockIdx.y;
    const int b     = bh >> 3;
    const int h     = bh & 7;
    const int qtile = blockIdx.x;        // 0..63
    const int tid   = threadIdx.x;       // 0..127
    const int wid   = tid >> 6;
    const int lane  = tid & 63;
    const int col   = lane & 15;
    const int g     = lane >> 4;         // 0..3
    const int qrow0 = qtile * 32 + wid * 16;
    const int cn    = cnt[b];
    const int nt    = (cn + KT - 1) >> 6;

    const unsigned short* KxB = Kxg + (size_t)bh * S * 32;
    const unsigned short* BtB = Btg + (size_t)bh * S * 32;

    bf16x8 qh, ql;
    {
        const float* qp = Q + ((size_t)bh * S + qrow0 + col) * HD + 8 * (g & 1);
        #pragma unroll
        for (int i = 0; i < 8; ++i) {
            const float f = qp[i];
            const unsigned short hi = f2b(f);
            qh[i] = (short)hi;
            ql[i] = (short)f2b(f - b2f(hi));
        }
    }

    float m = -1e30f, l = 0.f;
    f32x4 acc = {0.f, 0.f, 0.f, 0.f};

#define LOADT(KA, VB, TBASE)                                              \
    {                                                                     \
        const int base_ = (TBASE);                                        \
        _Pragma("unroll")                                                 \
        for (int kb = 0; kb < 4; ++kb) {                                  \
            KA[kb] = *(const bf16x8*)(                                    \
                KxB + (size_t)(base_ + kb * 16 + col) * 32 + 8 * g);      \
            VB[kb] = *(const bf16x8*)(                                    \
                BtB + (size_t)((base_ >> 4) + kb) * 512 + col * 32 + 8 * g); \
        }                                                                 \
    }

#define COMPUTE(KA, VB, TBASE)                                            \
    {                                                                     \
        const int base_ = (TBASE);                                        \
        f32x4 sc[4];                                                      \
        _Pragma("unroll")                                                 \
        for (int kb = 0; kb < 4; ++kb) {                                  \
            f32x4 c_ = {0.f, 0.f, 0.f, 0.f};                              \
            c_ = __builtin_amdgcn_mfma_f32_16x16x32_bf16(KA[kb], qh, c_, 0, 0, 0); \
            c_ = __builtin_amdgcn_mfma_f32_16x16x32_bf16(KA[kb], ql, c_, 0, 0, 0); \
            sc[kb] = c_;                                                  \
        }                                                                 \
        if (base_ + KT > cn) {                                            \
            _Pragma("unroll")                                             \
            for (int kb = 0; kb < 4; ++kb)                                \
                _Pragma("unroll")                                         \
                for (int r = 0; r < 4; ++r)                               \
                    if (base_ + kb * 16 + 4 * g + r >= cn) sc[kb][r] = -1e30f; \
        }                                                                 \
        float tm = sc[0][0];                                              \
        _Pragma("unroll")                                                 \
        for (int kb = 0; kb < 4; ++kb)                                    \
            _Pragma("unroll")                                             \
            for (int r = 0; r < 4; ++r) tm = fmaxf(tm, sc[kb][r]);        \
        tm = fmaxf(tm, __shfl_xor(tm, 16));                               \
        tm = fmaxf(tm, __shfl_xor(tm, 32));                               \
        if (__any(tm > m)) {                                              \
            const float mn = fmaxf(m, tm);                                \
            const float alpha = __expf(m - mn);                           \
            m = mn;                                                       \
            l *= alpha;                                                   \
            _Pragma("unroll")                                             \
            for (int r = 0; r < 4; ++r)                                   \
                acc[r] *= __shfl(alpha, 4 * g + r);                       \
        }                                                                 \
        _Pragma("unroll")                                                 \
        for (int kb = 0; kb < 4; ++kb) {                                  \
            const float p0 = __expf(sc[kb][0] - m);                       \
            const float p1 = __expf(sc[kb][1] - m);                       \
            const float p2 = __expf(sc[kb][2] - m);                       \
            const float p3 = __expf(sc[kb][3] - m);                       \
            l += (p0 + p1) + (p2 + p3);                                   \
            union { unsigned u[4]; bf16x8 v; } pa;                        \
            const unsigned b0 = (unsigned)f2b(p0);                        \
            const unsigned b1 = (unsigned)f2b(p1);                        \
            const unsigned b2 = (unsigned)f2b(p2);                        \
            const unsigned b3 = (unsigned)f2b(p3);                        \
            pa.u[0] = b0 | (b0 << 16);                                    \
            pa.u[1] = b1 | (b1 << 16);                                    \
            pa.u[2] = b2 | (b2 << 16);                                    \
            pa.u[3] = b3 | (b3 << 16);                                    \
            acc = __builtin_amdgcn_mfma_f32_16x16x32_bf16(pa.v, VB[kb], acc, 0, 0, 0); \
        }                                                                 \
    }

    bf16x8 kaA[4], vbA[4], kaB[4], vbB[4];
    LOADT(kaA, vbA, 0);
    for (int kt = 0; kt < nt; kt += 2) {
        if (kt + 1 < nt) LOADT(kaB, vbB, (kt + 1) * KT);
        COMPUTE(kaA, vbA, kt * KT);
        if (kt + 1 < nt) {
            if (kt + 2 < nt) LOADT(kaA, vbA, (kt + 2) * KT);
            COMPUTE(kaB, vbB, (kt + 1) * KT);
        }
    }
#undef LOADT
#undef COMPUTE

    l += __shfl_xor(l, 16);
    l += __shfl_xor(l, 32);

    const float inv = 1.f / l;
    #pragma unroll
    for (int r = 0; r < 4; ++r) {
        const float ir = __shfl(inv, 4 * g + r);
        out[((size_t)(b * S + qrow0 + 4 * g + r)) * E + col * 8 + h] = acc[r] * ir;
    }
}

extern "C" void kernel_launch(void* const* d_in, const int* in_sizes, int n_in,
                              void* d_out, int out_size, void* d_ws, size_t ws_size,
                              hipStream_t stream) {
    int ix = 0, im0 = -1, isc = -1, iw[3] = {-1, -1, -1}, nw = 0;
    for (int i = 0; i < n_in; ++i) {
        const int sz = in_sizes[i];
        if (sz == B * S * E) ix = i;
        else if (sz == B * S) { if (im0 < 0) im0 = i; }
        else if (sz == E * E) { if (nw < 3) iw[nw++] = i; }
        else if (sz == 1 && isc < 0) isc = i;
    }
    if (im0 < 0) im0 = 1;
    if (isc < 0) isc = 3;
    if (nw < 3) { iw[0] = n_in - 3; iw[1] = n_in - 2; iw[2] = n_in - 1; }

    const float* x        = (const float*)d_in[ix];
    const int*   src_mask = (const int*)d_in[im0];
    const int*   masked_p = (const int*)d_in[isc];
    const float* wq       = (const float*)d_in[iw[0]];
    const float* wk       = (const float*)d_in[iw[1]];
    const float* wv       = (const float*)d_in[iw[2]];
    float*       out      = (float*)d_out;

    float*          Qw  = (float*)d_ws;
    unsigned short* Kxg = (unsigned short*)(Qw + (size_t)BH * S * HD);
    unsigned short* Btg = Kxg + (size_t)BH * S * 32;
    int*            pos = (int*)(Btg + (size_t)BH * S * 32);
    int*            cnt = pos + B * S;

    prep<<<BH, 64, 0, stream>>>(src_mask, masked_p, pos, cnt, Kxg, Btg);
    qkv_proj<<<B * S / RPB, 384, 0, stream>>>(x, wq, wk, wv, pos, Qw, Kxg, Btg);
    attn<<<dim3(S / 32, BH), 128, 0, stream>>>(Qw, Kxg, Btg, cnt, out);
}

// Round 34
// 46.692 us; speedup vs baseline: 1.2072x; 1.0399x over previous
//
#include <hip/hip_runtime.h>
#include <hip/hip_bf16.h>

#define B 2
#define S 2048
#define E 128
#define H 8
#define HD 16
#define BH (B*H)

#define RPB 4    // rows per block (qkv_proj)
#define KT 64    // key tile (attn)

typedef __attribute__((ext_vector_type(8))) short bf16x8;
typedef __attribute__((ext_vector_type(4))) float f32x4;

__device__ __forceinline__ unsigned short f2b(float f) {   // f32->bf16 RNE
    const unsigned u = __float_as_uint(f);
    return (unsigned short)((u + 0x7FFFu + ((u >> 16) & 1u)) >> 16);
}
__device__ __forceinline__ float b2f(unsigned short u) {
    return __uint_as_float((unsigned)u << 16);
}

// ---- Pass A: compaction + tail-zero fused. Grid BH x 64 threads. ----
// Bt layout (INTERLEAVED): Bt[bh][key>>4][dim][32], slot = 2*(key&15)+part.
__global__ __launch_bounds__(64) void prep(
    const int* __restrict__ mask, const int* __restrict__ masked_p,
    int* __restrict__ pos, int* __restrict__ cnt,
    unsigned short* __restrict__ Kxg, unsigned short* __restrict__ Btg)
{
    const int bh = blockIdx.x;
    const int b = bh >> 3, h = bh & 7;
    const int lane = threadIdx.x;
    const int masked = *masked_p;

    int v[32];
    #pragma unroll
    for (int c = 0; c < 32; ++c)
        v[c] = mask[b * S + c * 64 + lane];

    int base = 0;
    #pragma unroll
    for (int c = 0; c < 32; ++c) {
        const bool keep = (masked != 0) || (v[c] != 0);
        const unsigned long long bal = __ballot(keep);
        if (h == 0) {
            const int my = base + (int)__popcll(bal & ((1ULL << lane) - 1ULL));
            pos[b * S + c * 64 + lane] = keep ? my : -1;
        }
        base += (int)__popcll(bal);
    }
    int cn = base;
    if (cn == 0) {                         // all masked: -1000 shift cancels
        if (h == 0) {
            #pragma unroll
            for (int c = 0; c < 32; ++c)
                pos[b * S + c * 64 + lane] = c * 64 + lane;
        }
        cn = S;
    }
    if (h == 0 && lane == 0) cnt[b] = cn;

    const int pad = ((cn + KT - 1) / KT) * KT;   // 64-granule
    const int nrows = pad - cn;
    unsigned short* KxB = Kxg + (size_t)bh * S * 32;
    unsigned short* BtB = Btg + (size_t)bh * S * 32;
    for (int idx = lane; idx < nrows * 16; idx += 64) {
        const int row = cn + (idx >> 4), d = idx & 15;
        KxB[row * 32 + d]      = 0;
        KxB[row * 32 + 16 + d] = 0;
        BtB[((row >> 4) * 16 + d) * 32 + (row & 15) * 2]     = 0;
        BtB[((row >> 4) * 16 + d) * 32 + (row & 15) * 2 + 1] = 0;
    }
}

// ---- Pass 0: QKV projection, 3-way matrix split, RPB=4 (1024 blocks). ----
__global__ __launch_bounds__(384) void qkv_proj(
    const float* __restrict__ x,
    const float* __restrict__ wq,
    const float* __restrict__ wk,
    const float* __restrict__ wv,
    const int* __restrict__ pos,
    float* __restrict__ Q,
    unsigned short* __restrict__ Kxg, unsigned short* __restrict__ Btg)
{
    __shared__ float xs[RPB][E];
    const int row0 = blockIdx.x * RPB;
    const int tid  = threadIdx.x;        // 0..383
    const int mat  = tid >> 7;           // 0=q, 1=k, 2=v (wave-uniform)
    const int c    = tid & 127;          // output column

    for (int idx = tid; idx < RPB * E; idx += 384)
        ((float*)xs)[idx] = x[(size_t)row0 * E + idx];
    __syncthreads();

    const float* w = (mat == 0) ? wq : (mat == 1) ? wk : wv;
    float a[RPB];
    #pragma unroll
    for (int rr = 0; rr < RPB; ++rr) a[rr] = 0.f;

    for (int i = 0; i < E; ++i) {
        const float wv_ = w[i * E + c];
        #pragma unroll
        for (int rr = 0; rr < RPB; ++rr)
            a[rr] = fmaf(xs[rr][i], wv_, a[rr]);
    }

    const int h = c & 7, d = c >> 3;     // faithful split: col = d*8+h
    if (mat == 0) {
        #pragma unroll
        for (int rr = 0; rr < RPB; ++rr) {
            const int row = row0 + rr;
            const int b = row >> 11, s = row & 2047;
            Q[(((size_t)(b * H + h)) * S + s) * HD + d] = a[rr] * 0.25f;
        }
    } else if (mat == 1) {
        #pragma unroll
        for (int rr = 0; rr < RPB; ++rr) {
            const int row = row0 + rr;
            const int p_ = pos[row];
            if (p_ >= 0) {
                const int b = row >> 11;
                const unsigned short kh = f2b(a[rr]);
                const unsigned short kl = f2b(a[rr] - b2f(kh));
                unsigned short* kx = Kxg + (size_t)(b * H + h) * S * 32
                                   + (size_t)p_ * 32;
                kx[d]      = kh;
                kx[16 + d] = kl;
            }
        }
    } else {
        #pragma unroll
        for (int rr = 0; rr < RPB; ++rr) {
            const int row = row0 + rr;
            const int p_ = pos[row];
            if (p_ >= 0) {
                const int b = row >> 11;
                const unsigned short vh = f2b(a[rr]);
                const unsigned short vl = f2b(a[rr] - b2f(vh));
                unsigned short* bt = Btg + (size_t)(b * H + h) * S * 32
                                   + ((size_t)(p_ >> 4) * 16 + d) * 32
                                   + (p_ & 15) * 2;
                *(unsigned*)bt = (unsigned)vh | ((unsigned)vl << 16);
            }
        }
    }
}

// ---- Pass 1: MFMA flash attention, KT=64, VGPR capped for 4 waves/EU. ----
__global__ __launch_bounds__(128, 4) void attn(
    const float* __restrict__ Q,
    const unsigned short* __restrict__ Kxg,
    const unsigned short* __restrict__ Btg,
    const int* __restrict__ cnt,
    float* __restrict__ out)
{
    const int bh    = blockIdx.y;
    const int b     = bh >> 3;
    const int h     = bh & 7;
    const int qtile = blockIdx.x;        // 0..63
    const int tid   = threadIdx.x;       // 0..127
    const int wid   = tid >> 6;
    const int lane  = tid & 63;
    const int col   = lane & 15;
    const int g     = lane >> 4;         // 0..3
    const int qrow0 = qtile * 32 + wid * 16;
    const int cn    = cnt[b];
    const int nt    = (cn + KT - 1) >> 6;

    const unsigned short* KxB = Kxg + (size_t)bh * S * 32;
    const unsigned short* BtB = Btg + (size_t)bh * S * 32;

    bf16x8 qh, ql;
    {
        const float* qp = Q + ((size_t)bh * S + qrow0 + col) * HD + 8 * (g & 1);
        #pragma unroll
        for (int i = 0; i < 8; ++i) {
            const float f = qp[i];
            const unsigned short hi = f2b(f);
            qh[i] = (short)hi;
            ql[i] = (short)f2b(f - b2f(hi));
        }
    }

    float m = -1e30f, l = 0.f;
    f32x4 acc = {0.f, 0.f, 0.f, 0.f};

#define LOADT(KA, VB, TBASE)                                              \
    {                                                                     \
        const int base_ = (TBASE);                                        \
        _Pragma("unroll")                                                 \
        for (int kb = 0; kb < 4; ++kb) {                                  \
            KA[kb] = *(const bf16x8*)(                                    \
                KxB + (size_t)(base_ + kb * 16 + col) * 32 + 8 * g);      \
            VB[kb] = *(const bf16x8*)(                                    \
                BtB + (size_t)((base_ >> 4) + kb) * 512 + col * 32 + 8 * g); \
        }                                                                 \
    }

#define COMPUTE(KA, VB, TBASE)                                            \
    {                                                                     \
        const int base_ = (TBASE);                                        \
        f32x4 sc[4];                                                      \
        _Pragma("unroll")                                                 \
        for (int kb = 0; kb < 4; ++kb) {                                  \
            f32x4 c_ = {0.f, 0.f, 0.f, 0.f};                              \
            c_ = __builtin_amdgcn_mfma_f32_16x16x32_bf16(KA[kb], qh, c_, 0, 0, 0); \
            c_ = __builtin_amdgcn_mfma_f32_16x16x32_bf16(KA[kb], ql, c_, 0, 0, 0); \
            sc[kb] = c_;                                                  \
        }                                                                 \
        if (base_ + KT > cn) {                                            \
            _Pragma("unroll")                                             \
            for (int kb = 0; kb < 4; ++kb)                                \
                _Pragma("unroll")                                         \
                for (int r = 0; r < 4; ++r)                               \
                    if (base_ + kb * 16 + 4 * g + r >= cn) sc[kb][r] = -1e30f; \
        }                                                                 \
        float tm = sc[0][0];                                              \
        _Pragma("unroll")                                                 \
        for (int kb = 0; kb < 4; ++kb)                                    \
            _Pragma("unroll")                                             \
            for (int r = 0; r < 4; ++r) tm = fmaxf(tm, sc[kb][r]);        \
        tm = fmaxf(tm, __shfl_xor(tm, 16));                               \
        tm = fmaxf(tm, __shfl_xor(tm, 32));                               \
        if (__any(tm > m)) {                                              \
            const float mn = fmaxf(m, tm);                                \
            const float alpha = __expf(m - mn);                           \
            m = mn;                                                       \
            l *= alpha;                                                   \
            _Pragma("unroll")                                             \
            for (int r = 0; r < 4; ++r)                                   \
                acc[r] *= __shfl(alpha, 4 * g + r);                       \
        }                                                                 \
        _Pragma("unroll")                                                 \
        for (int kb = 0; kb < 4; ++kb) {                                  \
            const float p0 = __expf(sc[kb][0] - m);                       \
            const float p1 = __expf(sc[kb][1] - m);                       \
            const float p2 = __expf(sc[kb][2] - m);                       \
            const float p3 = __expf(sc[kb][3] - m);                       \
            l += (p0 + p1) + (p2 + p3);                                   \
            union { unsigned u[4]; bf16x8 v; } pa;                        \
            const unsigned b0 = (unsigned)f2b(p0);                        \
            const unsigned b1 = (unsigned)f2b(p1);                        \
            const unsigned b2 = (unsigned)f2b(p2);                        \
            const unsigned b3 = (unsigned)f2b(p3);                        \
            pa.u[0] = b0 | (b0 << 16);                                    \
            pa.u[1] = b1 | (b1 << 16);                                    \
            pa.u[2] = b2 | (b2 << 16);                                    \
            pa.u[3] = b3 | (b3 << 16);                                    \
            acc = __builtin_amdgcn_mfma_f32_16x16x32_bf16(pa.v, VB[kb], acc, 0, 0, 0); \
        }                                                                 \
    }

    bf16x8 kaA[4], vbA[4], kaB[4], vbB[4];
    LOADT(kaA, vbA, 0);
    for (int kt = 0; kt < nt; kt += 2) {
        if (kt + 1 < nt) LOADT(kaB, vbB, (kt + 1) * KT);
        COMPUTE(kaA, vbA, kt * KT);
        if (kt + 1 < nt) {
            if (kt + 2 < nt) LOADT(kaA, vbA, (kt + 2) * KT);
            COMPUTE(kaB, vbB, (kt + 1) * KT);
        }
    }
#undef LOADT
#undef COMPUTE

    l += __shfl_xor(l, 16);
    l += __shfl_xor(l, 32);

    const float inv = 1.f / l;
    #pragma unroll
    for (int r = 0; r < 4; ++r) {
        const float ir = __shfl(inv, 4 * g + r);
        out[((size_t)(b * S + qrow0 + 4 * g + r)) * E + col * 8 + h] = acc[r] * ir;
    }
}

extern "C" void kernel_launch(void* const* d_in, const int* in_sizes, int n_in,
                              void* d_out, int out_size, void* d_ws, size_t ws_size,
                              hipStream_t stream) {
    int ix = 0, im0 = -1, isc = -1, iw[3] = {-1, -1, -1}, nw = 0;
    for (int i = 0; i < n_in; ++i) {
        const int sz = in_sizes[i];
        if (sz == B * S * E) ix = i;
        else if (sz == B * S) { if (im0 < 0) im0 = i; }
        else if (sz == E * E) { if (nw < 3) iw[nw++] = i; }
        else if (sz == 1 && isc < 0) isc = i;
    }
    if (im0 < 0) im0 = 1;
    if (isc < 0) isc = 3;
    if (nw < 3) { iw[0] = n_in - 3; iw[1] = n_in - 2; iw[2] = n_in - 1; }

    const float* x        = (const float*)d_in[ix];
    const int*   src_mask = (const int*)d_in[im0];
    const int*   masked_p = (const int*)d_in[isc];
    const float* wq       = (const float*)d_in[iw[0]];
    const float* wk       = (const float*)d_in[iw[1]];
    const float* wv       = (const float*)d_in[iw[2]];
    float*       out      = (float*)d_out;

    float*          Qw  = (float*)d_ws;
    unsigned short* Kxg = (unsigned short*)(Qw + (size_t)BH * S * HD);
    unsigned short* Btg = Kxg + (size_t)BH * S * 32;
    int*            pos = (int*)(Btg + (size_t)BH * S * 32);
    int*            cnt = pos + B * S;

    prep<<<BH, 64, 0, stream>>>(src_mask, masked_p, pos, cnt, Kxg, Btg);
    qkv_proj<<<B * S / RPB, 384, 0, stream>>>(x, wq, wk, wv, pos, Qw, Kxg, Btg);
    attn<<<dim3(S / 32, BH), 128, 0, stream>>>(Qw, Kxg, Btg, cnt, out);
}